// Round 1
// baseline (1190.937 us; speedup 1.0000x reference)
//
#include <hip/hip_runtime.h>

// ============================================================================
// RegionNonLocalEnhancedDenseBlock on MI355X (gfx950)
// Round 0: correctness-first.
//  - Attention: per-cell flash-style, bf16 MFMA 16x16x32 for QK^T / PV / Q-gen /
//    Wo-proj; pooled K/V via fp32 VALU. 1 block (4 waves) per cell.
//  - Dense convs: fp32 direct conv, LDS input tiles, scalarized weight loads.
//  - Fusion 1x1 + residual: fp32, thread-per-pixel.
// ws layout (floats): f0[16777216] f1[8388608] f2[8388608] f3[8388608]
//                     wkv[4096] w1p[18432] w2p[27648] w3p[36864] wfp[10240]
// ============================================================================

typedef short s16x8 __attribute__((ext_vector_type(8)));
typedef float f32x4 __attribute__((ext_vector_type(4)));

static_assert(sizeof(s16x8) == 16, "frag size");

__device__ __forceinline__ unsigned short f2bf(float f) {
  union { float f; unsigned int u; } v; v.f = f;
  unsigned int r = v.u + 0x7fffu + ((v.u >> 16) & 1u);  // RNE
  return (unsigned short)(r >> 16);
}

// ---------------------------------------------------------------------------
// Weight repack: wkv[c][64] = {Wk[o][c], Wv[o][c]}; conv w -> [ic][ky][kx][o];
// wf -> [ic][o]
// ---------------------------------------------------------------------------
__global__ void repack_kernel(const float* __restrict__ Wk, const float* __restrict__ Wv,
                              const float* __restrict__ W1, const float* __restrict__ W2,
                              const float* __restrict__ W3, const float* __restrict__ Wf,
                              float* __restrict__ wkv, float* __restrict__ w1p,
                              float* __restrict__ w2p, float* __restrict__ w3p,
                              float* __restrict__ wfp)
{
  const int i = blockIdx.x * 256 + threadIdx.x;
  if (i < 4096) {
    int c = i >> 6, o = i & 63;
    wkv[i] = (o < 32) ? Wk[o * 64 + c] : Wv[(o - 32) * 64 + c];
  }
  if (i < 18432) {  // W1: [32][64][3][3] -> [ic*3+ky)*3+kx][32]
    int o = i & 31; int r = i >> 5; int kx = r % 3; r /= 3; int ky = r % 3; int ic = r / 3;
    w1p[i] = W1[((o * 64 + ic) * 3 + ky) * 3 + kx];
  }
  if (i < 27648) {  // W2: in=96
    int o = i & 31; int r = i >> 5; int kx = r % 3; r /= 3; int ky = r % 3; int ic = r / 3;
    w2p[i] = W2[((o * 96 + ic) * 3 + ky) * 3 + kx];
  }
  if (i < 36864) {  // W3: in=128
    int o = i & 31; int r = i >> 5; int kx = r % 3; r /= 3; int ky = r % 3; int ic = r / 3;
    w3p[i] = W3[((o * 128 + ic) * 3 + ky) * 3 + kx];
  }
  if (i < 10240) {  // Wf: [64][160] -> [160][64]
    int o = i & 63, ic = i >> 6;
    wfp[i] = Wf[o * 160 + ic];
  }
}

// ---------------------------------------------------------------------------
// Attention: one block per cell (256 cells), 256 threads = 4 waves.
// Each wave owns 256 q-positions (16 M-tiles of 16).
// MFMA 16x16x32 bf16 layouts (verified in guide):
//   A[m=lane&15][k=quad*8+j], B[k=quad*8+j][n=lane&15],
//   D[row=quad*4+reg][col=lane&15]
// ---------------------------------------------------------------------------
__global__ __launch_bounds__(256) void attn_kernel(
    const float* __restrict__ x, const float* __restrict__ wkv,
    const float* __restrict__ bk, const float* __restrict__ bv,
    const float* __restrict__ Wq, const float* __restrict__ bq,
    const float* __restrict__ Wo, const float* __restrict__ bo,
    const float* __restrict__ gamma_p, float* __restrict__ f0)
{
  // strides padded for 2-way-max bank aliasing on b128 frag reads
  __shared__ __attribute__((aligned(16))) unsigned short kc[256 * 40];   // [kpos][ch]
  __shared__ __attribute__((aligned(16))) unsigned short vct[32 * 264];  // [ch][kpos]
  __shared__ __attribute__((aligned(16))) unsigned short qt[4][16 * 40]; // per-wave [m][ch]
  __shared__ __attribute__((aligned(16))) unsigned short pt[4][16 * 136];// per-wave [m][k-half]

  const int cell = blockIdx.x;
  const int n  = cell >> 6;
  const int gh = (cell >> 3) & 7;
  const int gw = cell & 7;
  const int y0 = gh * 32, xc0 = gw * 32;
  const int tid  = threadIdx.x;
  const int lane = tid & 63;
  const int wv   = tid >> 6;
  const int quad = lane >> 4;
  const int l15  = lane & 15;

  const float* xn  = x  + (size_t)n * (64 * 65536);
  float*       f0n = f0 + (size_t)n * (64 * 65536);

  // ---- stage 1: pooled K (into kc) and V (transposed into vct) ----
  {
    const int pi = tid >> 4, pj = tid & 15;
    float km[32], vm[32];
#pragma unroll
    for (int o = 0; o < 32; ++o) { km[o] = -3e38f; vm[o] = -3e38f; }
#pragma unroll
    for (int d = 0; d < 4; ++d) {
      const int yy = pi * 2 + (d >> 1), xx = pj * 2 + (d & 1);
      const float* px = xn + (y0 + yy) * 256 + xc0 + xx;
      float ka[32], va[32];
#pragma unroll
      for (int o = 0; o < 32; ++o) { ka[o] = 0.f; va[o] = 0.f; }
#pragma unroll 4
      for (int c = 0; c < 64; ++c) {
        const float xv = px[(size_t)c * 65536];
        const float* wr = wkv + c * 64;
#pragma unroll
        for (int o = 0; o < 32; ++o) {
          ka[o] += wr[o] * xv;
          va[o] += wr[32 + o] * xv;
        }
      }
#pragma unroll
      for (int o = 0; o < 32; ++o) {
        km[o] = fmaxf(km[o], ka[o]);
        vm[o] = fmaxf(vm[o], va[o]);
      }
    }
#pragma unroll
    for (int o = 0; o < 32; ++o) {
      kc[tid * 40 + o]   = f2bf(km[o] + bk[o]);   // bias after max (max(a+b)=max(a)+b)
      vct[o * 264 + tid] = f2bf(vm[o] + bv[o]);
    }
  }
  __syncthreads();

  const float gamma = gamma_p[0];

  // ---- preload Wq / Wo B-fragments (constant over all tiles) ----
  s16x8 wqf[2][2];  // [kstep][ntile]: Wq[c=nt*16+l15][ic=ks*32+quad*8+j]
#pragma unroll
  for (int ks = 0; ks < 2; ++ks)
#pragma unroll
    for (int nt = 0; nt < 2; ++nt) {
      const float* p = Wq + (nt * 16 + l15) * 64 + ks * 32 + quad * 8;
      s16x8 t;
#pragma unroll
      for (int j = 0; j < 8; ++j) t[j] = (short)f2bf(p[j]);
      wqf[ks][nt] = t;
    }
  s16x8 wof[4];  // [ntile]: Wo[co=nt*16+l15][c=quad*8+j]
#pragma unroll
  for (int nt = 0; nt < 4; ++nt) {
    const float* p = Wo + (nt * 16 + l15) * 32 + quad * 8;
    s16x8 t;
#pragma unroll
    for (int j = 0; j < 8; ++j) t[j] = (short)f2bf(p[j]);
    wof[nt] = t;
  }
  float bqv[2]; bqv[0] = bq[l15]; bqv[1] = bq[16 + l15];
  float bov[4];
#pragma unroll
  for (int nt = 0; nt < 4; ++nt) bov[nt] = bo[nt * 16 + l15];

  unsigned short* qtw = qt[wv];
  unsigned short* ptw = pt[wv];
  const f32x4 zf = {0.f, 0.f, 0.f, 0.f};

  for (int mt = 0; mt < 16; ++mt) {
    const int pbase = wv * 256 + mt * 16;

    // ---- Q-gen: D[16 pos][32 ch] = X^T * Wq^T (+bq), 2 K-steps x 2 N-tiles
    f32x4 qd0 = zf, qd1 = zf;
    {
      const int p = pbase + l15;
      const int yy = p >> 5, xx = p & 31;
      const float* xp = xn + (y0 + yy) * 256 + xc0 + xx + (size_t)(quad * 8) * 65536;
#pragma unroll
      for (int ks = 0; ks < 2; ++ks) {
        s16x8 a;
#pragma unroll
        for (int j = 0; j < 8; ++j) a[j] = (short)f2bf(xp[(size_t)(ks * 32 + j) * 65536]);
        qd0 = __builtin_amdgcn_mfma_f32_16x16x32_bf16(a, wqf[ks][0], qd0, 0, 0, 0);
        qd1 = __builtin_amdgcn_mfma_f32_16x16x32_bf16(a, wqf[ks][1], qd1, 0, 0, 0);
      }
    }
#pragma unroll
    for (int i = 0; i < 4; ++i) {
      qtw[(quad * 4 + i) * 40 + l15]      = f2bf(qd0[i] + bqv[0]);
      qtw[(quad * 4 + i) * 40 + 16 + l15] = f2bf(qd1[i] + bqv[1]);
    }

    // ---- S = Q * K^T : 16 N-tiles, single K-step (K=32 channels)
    s16x8 qa = *(const s16x8*)&qtw[l15 * 40 + quad * 8];
    f32x4 S[16];
#pragma unroll
    for (int nt = 0; nt < 16; ++nt) {
      s16x8 kb = *(const s16x8*)&kc[(nt * 16 + l15) * 40 + quad * 8];
      S[nt] = __builtin_amdgcn_mfma_f32_16x16x32_bf16(qa, kb, zf, 0, 0, 0);
    }

    // ---- softmax over 256 cols; lane owns rows quad*4+i, col l15 of each tile
    float rl[4];
#pragma unroll
    for (int i = 0; i < 4; ++i) {
      float m = S[0][i];
#pragma unroll
      for (int nt = 1; nt < 16; ++nt) m = fmaxf(m, S[nt][i]);
#pragma unroll
      for (int d2 = 1; d2 < 16; d2 <<= 1) m = fmaxf(m, __shfl_xor(m, d2, 64));
      float s = 0.f;
#pragma unroll
      for (int nt = 0; nt < 16; ++nt) {
        float e = __expf(S[nt][i] - m);
        S[nt][i] = e;
        s += e;
      }
#pragma unroll
      for (int d2 = 1; d2 < 16; d2 <<= 1) s += __shfl_xor(s, d2, 64);
      rl[i] = s;  // divide folded into O (linear)
    }

    // ---- O = P * V over 2 halves of 128 k-positions (C->A layout via LDS)
    f32x4 O0 = zf, O1 = zf;
#pragma unroll
    for (int h = 0; h < 2; ++h) {
#pragma unroll
      for (int t = 0; t < 8; ++t) {
#pragma unroll
        for (int i = 0; i < 4; ++i)
          ptw[(quad * 4 + i) * 136 + t * 16 + l15] = f2bf(S[h * 8 + t][i]);
      }
#pragma unroll
      for (int kk = 0; kk < 4; ++kk) {
        s16x8 pa = *(const s16x8*)&ptw[l15 * 136 + kk * 32 + quad * 8];
        const int kb0 = h * 128 + kk * 32 + quad * 8;
        s16x8 vb0 = *(const s16x8*)&vct[l15 * 264 + kb0];
        s16x8 vb1 = *(const s16x8*)&vct[(16 + l15) * 264 + kb0];
        O0 = __builtin_amdgcn_mfma_f32_16x16x32_bf16(pa, vb0, O0, 0, 0, 0);
        O1 = __builtin_amdgcn_mfma_f32_16x16x32_bf16(pa, vb1, O1, 0, 0, 0);
      }
    }

    // ---- normalize, round-trip to A-layout, project with Wo, epilogue
#pragma unroll
    for (int i = 0; i < 4; ++i) {
      const float inv = 1.0f / rl[i];
      ptw[(quad * 4 + i) * 40 + l15]      = f2bf(O0[i] * inv);
      ptw[(quad * 4 + i) * 40 + 16 + l15] = f2bf(O1[i] * inv);
    }
    s16x8 oa = *(const s16x8*)&ptw[l15 * 40 + quad * 8];
#pragma unroll
    for (int nt = 0; nt < 4; ++nt) {
      f32x4 D = __builtin_amdgcn_mfma_f32_16x16x32_bf16(oa, wof[nt], zf, 0, 0, 0);
      const int co = nt * 16 + l15;
#pragma unroll
      for (int i = 0; i < 4; ++i) {
        const int p = pbase + quad * 4 + i;
        const int yy = p >> 5, xx = p & 31;
        const size_t g = (size_t)co * 65536 + (size_t)(y0 + yy) * 256 + xc0 + xx;
        f0n[g] = gamma * (D[i] + bov[nt]) + xn[g];  // gamma*(Wo.att+bo) + x
      }
    }
  }
}

// ---------------------------------------------------------------------------
// conv3x3 (pad 1) + ReLU, 32 output channels. Input channels = NCHUNK*16,
// gathered from up to 3 concatenated sources (f0:64, f1:32, f2:32).
// Block: 256 thr = 32x8 output pixels; per-thread 32 output-channel accs.
// ---------------------------------------------------------------------------
template <int NCHUNK>
__global__ __launch_bounds__(256) void conv3_kernel(
    const float* __restrict__ s0, const float* __restrict__ s1,
    const float* __restrict__ s2, const float* __restrict__ wp,
    const float* __restrict__ bias, float* __restrict__ out)
{
  __shared__ float tile[16][10][34];

  const int bid = blockIdx.x;
  const int n = bid >> 8;
  const int t = bid & 255;
  const int ty0 = (t >> 3) * 8;   // 32 y-tiles of 8 rows
  const int tx0 = (t & 7) * 32;   // 8 x-tiles of 32 cols
  const int tid = threadIdx.x;
  const int tx = tid & 31, ty = tid >> 5;

  float acc[32];
#pragma unroll
  for (int o = 0; o < 32; ++o) acc[o] = bias[o];

  for (int ch = 0; ch < NCHUNK; ++ch) {
    const float* src;
    if (ch < 4)      src = s0 + (size_t)n * (64 * 65536) + (size_t)ch * (16 * 65536);
    else if (ch < 6) src = s1 + (size_t)n * (32 * 65536) + (size_t)(ch - 4) * (16 * 65536);
    else             src = s2 + (size_t)n * (32 * 65536) + (size_t)(ch - 6) * (16 * 65536);

    __syncthreads();  // WAR: previous chunk's reads done
    for (int idx = tid; idx < 16 * 10 * 34; idx += 256) {
      const int c = idx / 340;
      const int rem = idx % 340;
      const int r = rem / 34;
      const int col = rem % 34;
      const int gy = ty0 + r - 1, gx = tx0 + col - 1;
      float v = 0.f;
      if (gy >= 0 && gy < 256 && gx >= 0 && gx < 256)
        v = src[(size_t)c * 65536 + gy * 256 + gx];
      tile[c][r][col] = v;
    }
    __syncthreads();

    const float* wc = wp + ch * (16 * 9 * 32);
#pragma unroll 1
    for (int ic = 0; ic < 16; ++ic) {
#pragma unroll
      for (int ky = 0; ky < 3; ++ky) {
        const float a0 = tile[ic][ty + ky][tx];
        const float a1 = tile[ic][ty + ky][tx + 1];
        const float a2 = tile[ic][ty + ky][tx + 2];
        const float* wr = wc + (ic * 3 + ky) * 96;  // [kx][32 o], uniform -> s_load
#pragma unroll
        for (int o = 0; o < 32; ++o)
          acc[o] += wr[o] * a0 + wr[32 + o] * a1 + wr[64 + o] * a2;
      }
    }
  }

  const size_t obase = (size_t)n * (32 * 65536) + (size_t)(ty0 + ty) * 256 + tx0 + tx;
#pragma unroll
  for (int o = 0; o < 32; ++o)
    out[obase + (size_t)o * 65536] = fmaxf(acc[o], 0.f);
}

// ---------------------------------------------------------------------------
// fusion 1x1 over concat(f0,f1,f2,f3) [160 ch] -> 64 ch, + bias + residual x
// ---------------------------------------------------------------------------
__global__ __launch_bounds__(256) void fuse_kernel(
    const float* __restrict__ f0, const float* __restrict__ f1,
    const float* __restrict__ f2, const float* __restrict__ f3,
    const float* __restrict__ x, const float* __restrict__ wfp,
    const float* __restrict__ bf, float* __restrict__ out)
{
  const int bid = blockIdx.x;
  const int n = bid >> 8;
  const int p = (bid & 255) * 256 + threadIdx.x;

  float acc[64];
#pragma unroll
  for (int o = 0; o < 64; ++o) acc[o] = bf[o];

  const float* b0 = f0 + (size_t)n * (64 * 65536) + p;
  const float* b1 = f1 + (size_t)n * (32 * 65536) + p;
  const float* b2 = f2 + (size_t)n * (32 * 65536) + p;
  const float* b3 = f3 + (size_t)n * (32 * 65536) + p;

#pragma unroll 2
  for (int c = 0; c < 64; ++c) {
    const float v = b0[(size_t)c * 65536];
    const float* wr = wfp + c * 64;
#pragma unroll
    for (int o = 0; o < 64; ++o) acc[o] += wr[o] * v;
  }
#pragma unroll 2
  for (int c = 0; c < 32; ++c) {
    const float v = b1[(size_t)c * 65536];
    const float* wr = wfp + (64 + c) * 64;
#pragma unroll
    for (int o = 0; o < 64; ++o) acc[o] += wr[o] * v;
  }
#pragma unroll 2
  for (int c = 0; c < 32; ++c) {
    const float v = b2[(size_t)c * 65536];
    const float* wr = wfp + (96 + c) * 64;
#pragma unroll
    for (int o = 0; o < 64; ++o) acc[o] += wr[o] * v;
  }
#pragma unroll 2
  for (int c = 0; c < 32; ++c) {
    const float v = b3[(size_t)c * 65536];
    const float* wr = wfp + (128 + c) * 64;
#pragma unroll
    for (int o = 0; o < 64; ++o) acc[o] += wr[o] * v;
  }

  const float* xp = x + (size_t)n * (64 * 65536) + p;
  float* op = out + (size_t)n * (64 * 65536) + p;
#pragma unroll
  for (int o = 0; o < 64; ++o)
    op[(size_t)o * 65536] = acc[o] + xp[(size_t)o * 65536];
}

// ---------------------------------------------------------------------------
extern "C" void kernel_launch(void* const* d_in, const int* in_sizes, int n_in,
                              void* d_out, int out_size, void* d_ws, size_t ws_size,
                              hipStream_t stream)
{
  const float* x     = (const float*)d_in[0];
  const float* Wq    = (const float*)d_in[1];
  const float* bq    = (const float*)d_in[2];
  const float* Wk    = (const float*)d_in[3];
  const float* bk    = (const float*)d_in[4];
  const float* Wv    = (const float*)d_in[5];
  const float* bv    = (const float*)d_in[6];
  const float* Wo    = (const float*)d_in[7];
  const float* bo    = (const float*)d_in[8];
  const float* gamma = (const float*)d_in[9];
  const float* W1    = (const float*)d_in[10];
  const float* b1    = (const float*)d_in[11];
  const float* W2    = (const float*)d_in[12];
  const float* b2    = (const float*)d_in[13];
  const float* W3    = (const float*)d_in[14];
  const float* b3    = (const float*)d_in[15];
  const float* Wf    = (const float*)d_in[16];
  const float* bf    = (const float*)d_in[17];

  float* out = (float*)d_out;
  float* ws  = (float*)d_ws;

  float* f0  = ws;
  float* f1  = ws + 16777216;
  float* f2  = ws + 25165824;
  float* f3  = ws + 33554432;
  float* wkv = ws + 41943040;
  float* w1p = wkv + 4096;
  float* w2p = w1p + 18432;
  float* w3p = w2p + 27648;
  float* wfp = w3p + 36864;

  repack_kernel<<<144, 256, 0, stream>>>(Wk, Wv, W1, W2, W3, Wf, wkv, w1p, w2p, w3p, wfp);
  attn_kernel<<<256, 256, 0, stream>>>(x, wkv, bk, bv, Wq, bq, Wo, bo, gamma, f0);
  conv3_kernel<4><<<1024, 256, 0, stream>>>(f0, f1, f2, w1p, b1, f1);
  conv3_kernel<6><<<1024, 256, 0, stream>>>(f0, f1, f2, w2p, b2, f2);
  conv3_kernel<8><<<1024, 256, 0, stream>>>(f0, f1, f2, w3p, b3, f3);
  fuse_kernel<<<1024, 256, 0, stream>>>(f0, f1, f2, f3, x, wfp, bf, out);
}

// Round 2
// 374.024 us; speedup vs baseline: 3.1841x; 3.1841x over previous
//
#include <hip/hip_runtime.h>

// ============================================================================
// RegionNonLocalEnhancedDenseBlock on MI355X (gfx950) — Round 2
//  - f0..f3 stored bf16 pixel-major [n][y][x][c] so conv/fuse A-frags need no
//    transpose and staging is b128 end-to-end.
//  - conv3x3: bf16 MFMA implicit GEMM (9 shifted taps), LDS tile pad-to-40.
//  - fuse 1x1: bf16 MFMA K=160, A-frags from global, LDS transpose epilogue.
//  - attention unchanged except f0 written bf16 [y][x][64].
// ============================================================================

typedef short s16x8 __attribute__((ext_vector_type(8)));
typedef float f32x4 __attribute__((ext_vector_type(4)));
typedef unsigned short ushort_t;

__device__ __forceinline__ unsigned short f2bf(float f) {
  union { float f; unsigned int u; } v; v.f = f;
  unsigned int r = v.u + 0x7fffu + ((v.u >> 16) & 1u);  // RNE
  return (unsigned short)(r >> 16);
}

// ---------------------------------------------------------------------------
// Repack: wkv fp32 [c][64]={Wk^T,Wv^T}; conv weights -> bf16 MFMA-B-frag order
// wc[tap][kg][o][j] = W[o][kg*8+j][ky][kx]; wff[kg][o][j] = Wf[o][kg*8+j]
// ---------------------------------------------------------------------------
__global__ void repack_kernel(const float* __restrict__ Wk, const float* __restrict__ Wv,
                              const float* __restrict__ W1, const float* __restrict__ W2,
                              const float* __restrict__ W3, const float* __restrict__ Wf,
                              float* __restrict__ wkv, ushort_t* __restrict__ wc1,
                              ushort_t* __restrict__ wc2, ushort_t* __restrict__ wc3,
                              ushort_t* __restrict__ wff)
{
  const int i = blockIdx.x * 256 + threadIdx.x;
  if (i < 4096) {
    int c = i >> 6, o = i & 63;
    wkv[i] = (o < 32) ? Wk[o * 64 + c] : Wv[(o - 32) * 64 + c];
  }
  if (i < 18432) {  // W1 [32][64][3][3], Kg=8
    int j = i & 7, o = (i >> 3) & 31, r = i >> 8, tap = r >> 3, kg = r & 7;
    wc1[i] = f2bf(W1[o * 576 + (kg * 8 + j) * 9 + tap]);
  }
  if (i < 27648) {  // W2 [32][96][3][3], Kg=12
    int j = i & 7, o = (i >> 3) & 31, r = i >> 8, tap = r / 12, kg = r % 12;
    wc2[i] = f2bf(W2[o * 864 + (kg * 8 + j) * 9 + tap]);
  }
  if (i < 36864) {  // W3 [32][128][3][3], Kg=16
    int j = i & 7, o = (i >> 3) & 31, r = i >> 8, tap = r >> 4, kg = r & 15;
    wc3[i] = f2bf(W3[o * 1152 + (kg * 8 + j) * 9 + tap]);
  }
  if (i < 10240) {  // Wf [64][160], Kg=20
    int j = i & 7, o = (i >> 3) & 63, kg = i >> 9;
    wff[i] = f2bf(Wf[o * 160 + kg * 8 + j]);
  }
}

// ---------------------------------------------------------------------------
// Attention: one block per cell (256 cells), 4 waves. Unchanged from round 1
// except f0 is written bf16 in [n][y][x][64] layout.
// ---------------------------------------------------------------------------
__global__ __launch_bounds__(256) void attn_kernel(
    const float* __restrict__ x, const float* __restrict__ wkv,
    const float* __restrict__ bk, const float* __restrict__ bv,
    const float* __restrict__ Wq, const float* __restrict__ bq,
    const float* __restrict__ Wo, const float* __restrict__ bo,
    const float* __restrict__ gamma_p, ushort_t* __restrict__ f0)
{
  __shared__ __attribute__((aligned(16))) unsigned short kc[256 * 40];
  __shared__ __attribute__((aligned(16))) unsigned short vct[32 * 264];
  __shared__ __attribute__((aligned(16))) unsigned short qt[4][16 * 40];
  __shared__ __attribute__((aligned(16))) unsigned short pt[4][16 * 136];

  const int cell = blockIdx.x;
  const int n  = cell >> 6;
  const int gh = (cell >> 3) & 7;
  const int gw = cell & 7;
  const int y0 = gh * 32, xc0 = gw * 32;
  const int tid  = threadIdx.x;
  const int lane = tid & 63;
  const int wv   = tid >> 6;
  const int quad = lane >> 4;
  const int l15  = lane & 15;

  const float* xn  = x  + (size_t)n * (64 * 65536);
  ushort_t*    f0n = f0 + (size_t)n * (65536 * 64);

  {
    const int pi = tid >> 4, pj = tid & 15;
    float km[32], vm[32];
#pragma unroll
    for (int o = 0; o < 32; ++o) { km[o] = -3e38f; vm[o] = -3e38f; }
#pragma unroll
    for (int d = 0; d < 4; ++d) {
      const int yy = pi * 2 + (d >> 1), xx = pj * 2 + (d & 1);
      const float* px = xn + (y0 + yy) * 256 + xc0 + xx;
      float ka[32], va[32];
#pragma unroll
      for (int o = 0; o < 32; ++o) { ka[o] = 0.f; va[o] = 0.f; }
#pragma unroll 4
      for (int c = 0; c < 64; ++c) {
        const float xv = px[(size_t)c * 65536];
        const float* wr = wkv + c * 64;
#pragma unroll
        for (int o = 0; o < 32; ++o) {
          ka[o] += wr[o] * xv;
          va[o] += wr[32 + o] * xv;
        }
      }
#pragma unroll
      for (int o = 0; o < 32; ++o) {
        km[o] = fmaxf(km[o], ka[o]);
        vm[o] = fmaxf(vm[o], va[o]);
      }
    }
#pragma unroll
    for (int o = 0; o < 32; ++o) {
      kc[tid * 40 + o]   = f2bf(km[o] + bk[o]);
      vct[o * 264 + tid] = f2bf(vm[o] + bv[o]);
    }
  }
  __syncthreads();

  const float gamma = gamma_p[0];

  s16x8 wqf[2][2];
#pragma unroll
  for (int ks = 0; ks < 2; ++ks)
#pragma unroll
    for (int nt = 0; nt < 2; ++nt) {
      const float* p = Wq + (nt * 16 + l15) * 64 + ks * 32 + quad * 8;
      s16x8 t;
#pragma unroll
      for (int j = 0; j < 8; ++j) t[j] = (short)f2bf(p[j]);
      wqf[ks][nt] = t;
    }
  s16x8 wof[4];
#pragma unroll
  for (int nt = 0; nt < 4; ++nt) {
    const float* p = Wo + (nt * 16 + l15) * 32 + quad * 8;
    s16x8 t;
#pragma unroll
    for (int j = 0; j < 8; ++j) t[j] = (short)f2bf(p[j]);
    wof[nt] = t;
  }
  float bqv[2]; bqv[0] = bq[l15]; bqv[1] = bq[16 + l15];
  float bov[4];
#pragma unroll
  for (int nt = 0; nt < 4; ++nt) bov[nt] = bo[nt * 16 + l15];

  unsigned short* qtw = qt[wv];
  unsigned short* ptw = pt[wv];
  const f32x4 zf = {0.f, 0.f, 0.f, 0.f};

  for (int mt = 0; mt < 16; ++mt) {
    const int pbase = wv * 256 + mt * 16;

    f32x4 qd0 = zf, qd1 = zf;
    {
      const int p = pbase + l15;
      const int yy = p >> 5, xx = p & 31;
      const float* xp = xn + (y0 + yy) * 256 + xc0 + xx + (size_t)(quad * 8) * 65536;
#pragma unroll
      for (int ks = 0; ks < 2; ++ks) {
        s16x8 a;
#pragma unroll
        for (int j = 0; j < 8; ++j) a[j] = (short)f2bf(xp[(size_t)(ks * 32 + j) * 65536]);
        qd0 = __builtin_amdgcn_mfma_f32_16x16x32_bf16(a, wqf[ks][0], qd0, 0, 0, 0);
        qd1 = __builtin_amdgcn_mfma_f32_16x16x32_bf16(a, wqf[ks][1], qd1, 0, 0, 0);
      }
    }
#pragma unroll
    for (int i = 0; i < 4; ++i) {
      qtw[(quad * 4 + i) * 40 + l15]      = f2bf(qd0[i] + bqv[0]);
      qtw[(quad * 4 + i) * 40 + 16 + l15] = f2bf(qd1[i] + bqv[1]);
    }

    s16x8 qa = *(const s16x8*)&qtw[l15 * 40 + quad * 8];
    f32x4 S[16];
#pragma unroll
    for (int nt = 0; nt < 16; ++nt) {
      s16x8 kb = *(const s16x8*)&kc[(nt * 16 + l15) * 40 + quad * 8];
      S[nt] = __builtin_amdgcn_mfma_f32_16x16x32_bf16(qa, kb, zf, 0, 0, 0);
    }

    float rl[4];
#pragma unroll
    for (int i = 0; i < 4; ++i) {
      float m = S[0][i];
#pragma unroll
      for (int nt = 1; nt < 16; ++nt) m = fmaxf(m, S[nt][i]);
#pragma unroll
      for (int d2 = 1; d2 < 16; d2 <<= 1) m = fmaxf(m, __shfl_xor(m, d2, 64));
      float s = 0.f;
#pragma unroll
      for (int nt = 0; nt < 16; ++nt) {
        float e = __expf(S[nt][i] - m);
        S[nt][i] = e;
        s += e;
      }
#pragma unroll
      for (int d2 = 1; d2 < 16; d2 <<= 1) s += __shfl_xor(s, d2, 64);
      rl[i] = s;
    }

    f32x4 O0 = zf, O1 = zf;
#pragma unroll
    for (int h = 0; h < 2; ++h) {
#pragma unroll
      for (int t = 0; t < 8; ++t) {
#pragma unroll
        for (int i = 0; i < 4; ++i)
          ptw[(quad * 4 + i) * 136 + t * 16 + l15] = f2bf(S[h * 8 + t][i]);
      }
#pragma unroll
      for (int kk = 0; kk < 4; ++kk) {
        s16x8 pa = *(const s16x8*)&ptw[l15 * 136 + kk * 32 + quad * 8];
        const int kb0 = h * 128 + kk * 32 + quad * 8;
        s16x8 vb0 = *(const s16x8*)&vct[l15 * 264 + kb0];
        s16x8 vb1 = *(const s16x8*)&vct[(16 + l15) * 264 + kb0];
        O0 = __builtin_amdgcn_mfma_f32_16x16x32_bf16(pa, vb0, O0, 0, 0, 0);
        O1 = __builtin_amdgcn_mfma_f32_16x16x32_bf16(pa, vb1, O1, 0, 0, 0);
      }
    }

#pragma unroll
    for (int i = 0; i < 4; ++i) {
      const float inv = 1.0f / rl[i];
      ptw[(quad * 4 + i) * 40 + l15]      = f2bf(O0[i] * inv);
      ptw[(quad * 4 + i) * 40 + 16 + l15] = f2bf(O1[i] * inv);
    }
    s16x8 oa = *(const s16x8*)&ptw[l15 * 40 + quad * 8];
#pragma unroll
    for (int nt = 0; nt < 4; ++nt) {
      f32x4 D = __builtin_amdgcn_mfma_f32_16x16x32_bf16(oa, wof[nt], zf, 0, 0, 0);
      const int co = nt * 16 + l15;
#pragma unroll
      for (int i = 0; i < 4; ++i) {
        const int p = pbase + quad * 4 + i;
        const int yy = p >> 5, xx = p & 31;
        const int pix = (y0 + yy) * 256 + xc0 + xx;
        const float r = gamma * (D[i] + bov[nt]) + xn[(size_t)co * 65536 + pix];
        f0n[(size_t)pix * 64 + co] = f2bf(r);
      }
    }
  }
}

// ---------------------------------------------------------------------------
// conv3x3 + ReLU via bf16 MFMA implicit GEMM.
// Block tile: 32x16 output pixels. LDS: [18 rows][34 cols][40 ch-pad] bf16.
// Per wave: rows 4*wv..4*wv+3, 2 x-halves, acc[4][2][2] (M=16 px, N=2x16 oc).
// Inputs bf16 [n][y][x][Csrc]; output bf16 [n][y][x][32].
// ---------------------------------------------------------------------------
template <int NCHUNK>
__global__ __launch_bounds__(256) void conv3_kernel(
    const ushort_t* __restrict__ s0, const ushort_t* __restrict__ s1,
    const ushort_t* __restrict__ s2, const ushort_t* __restrict__ wc,
    const float* __restrict__ bias, ushort_t* __restrict__ outp)
{
  __shared__ __attribute__((aligned(16))) ushort_t tile[612 * 40];

  const int bid = blockIdx.x;
  const int n = bid >> 7;
  const int t = bid & 127;
  const int ty0 = (t >> 3) * 16;
  const int tx0 = (t & 7) * 32;
  const int tid = threadIdx.x, lane = tid & 63, wv = tid >> 6;
  const int quad = lane >> 4, l15 = lane & 15;
  constexpr int Kg = NCHUNK * 4;

  const f32x4 zf = {0.f, 0.f, 0.f, 0.f};
  f32x4 acc[4][2][2];
#pragma unroll
  for (int r = 0; r < 4; ++r)
#pragma unroll
    for (int h = 0; h < 2; ++h) { acc[r][h][0] = zf; acc[r][h][1] = zf; }

  for (int ch = 0; ch < NCHUNK; ++ch) {
    const ushort_t* src; int cstr, cbase;
    if (ch < 2)       { src = s0 + (size_t)n * (65536 * 64); cstr = 64; cbase = ch * 32; }
    else if (ch == 2) { src = s1 + (size_t)n * (65536 * 32); cstr = 32; cbase = 0; }
    else              { src = s2 + (size_t)n * (65536 * 32); cstr = 32; cbase = 0; }

    __syncthreads();  // WAR on tile
    for (int u = tid; u < 2448; u += 256) {
      const int pix = u >> 2, cg = u & 3;
      const int lr = pix / 34, lc = pix - lr * 34;
      const int gy = ty0 - 1 + lr, gx = tx0 - 1 + lc;
      s16x8 v = {0, 0, 0, 0, 0, 0, 0, 0};
      if ((unsigned)gy < 256u && (unsigned)gx < 256u)
        v = *(const s16x8*)(src + (size_t)(gy * 256 + gx) * cstr + cbase + cg * 8);
      *(s16x8*)&tile[pix * 40 + cg * 8] = v;
    }
    __syncthreads();

#pragma unroll
    for (int tap = 0; tap < 9; ++tap) {
      const int ky = tap / 3, kx = tap - ky * 3;
      const ushort_t* wb = wc + ((size_t)(tap * Kg + ch * 4 + quad) * 32 + l15) * 8;
      const s16x8 b0 = *(const s16x8*)wb;
      const s16x8 b1 = *(const s16x8*)(wb + 128);
#pragma unroll
      for (int r = 0; r < 4; ++r) {
        const int lr = 4 * wv + r + ky;
#pragma unroll
        for (int h = 0; h < 2; ++h) {
          const int lc = h * 16 + l15 + kx;
          const s16x8 a = *(const s16x8*)&tile[(lr * 34 + lc) * 40 + quad * 8];
          acc[r][h][0] = __builtin_amdgcn_mfma_f32_16x16x32_bf16(a, b0, acc[r][h][0], 0, 0, 0);
          acc[r][h][1] = __builtin_amdgcn_mfma_f32_16x16x32_bf16(a, b1, acc[r][h][1], 0, 0, 0);
        }
      }
    }
  }

  const float bv0 = bias[l15], bv1 = bias[16 + l15];
  ushort_t* on = outp + (size_t)n * (65536 * 32);
#pragma unroll
  for (int r = 0; r < 4; ++r) {
    const int gy = ty0 + 4 * wv + r;
#pragma unroll
    for (int h = 0; h < 2; ++h) {
#pragma unroll
      for (int i = 0; i < 4; ++i) {
        const int gx = tx0 + h * 16 + quad * 4 + i;
        ushort_t* op = on + (size_t)(gy * 256 + gx) * 32;
        op[l15]      = f2bf(fmaxf(acc[r][h][0][i] + bv0, 0.f));
        op[16 + l15] = f2bf(fmaxf(acc[r][h][1][i] + bv1, 0.f));
      }
    }
  }
}

// ---------------------------------------------------------------------------
// fuse: out = cat(f0,f1,f2,f3)[160] x Wf^T [160x64] + bf + x, fp32 NCHW out.
// MFMA K=160 (5 ksteps), A-frags straight from global bf16 pixel-major.
// Per wave: 4 M-tiles of 16 pixels. LDS transpose for coalesced NCHW stores.
// ---------------------------------------------------------------------------
__global__ __launch_bounds__(256) void fuse_kernel(
    const ushort_t* __restrict__ f0, const ushort_t* __restrict__ f1,
    const ushort_t* __restrict__ f2, const ushort_t* __restrict__ f3,
    const float* __restrict__ x, const ushort_t* __restrict__ wff,
    const float* __restrict__ bfv, float* __restrict__ out)
{
  __shared__ float tr[4][64 * 17];

  const int tid = threadIdx.x, lane = tid & 63, wv = tid >> 6;
  const int quad = lane >> 4, l15 = lane & 15;

  s16x8 wf[5][4];
#pragma unroll
  for (int ks = 0; ks < 5; ++ks)
#pragma unroll
    for (int nt = 0; nt < 4; ++nt)
      wf[ks][nt] = *(const s16x8*)(wff + ((size_t)((ks * 4 + quad) * 64) + nt * 16 + l15) * 8);
  float bb[4];
#pragma unroll
  for (int nt = 0; nt < 4; ++nt) bb[nt] = bfv[nt * 16 + l15];

  const int wt = blockIdx.x * 4 + wv;
  const f32x4 zf = {0.f, 0.f, 0.f, 0.f};
  float* trw = tr[wv];

  for (int mt = 0; mt < 4; ++mt) {
    const int p0 = wt * 64 + mt * 16;
    const size_t pA = (size_t)(p0 + l15);
    const s16x8 a0 = *(const s16x8*)(f0 + pA * 64 + quad * 8);
    const s16x8 a1 = *(const s16x8*)(f0 + pA * 64 + 32 + quad * 8);
    const s16x8 a2 = *(const s16x8*)(f1 + pA * 32 + quad * 8);
    const s16x8 a3 = *(const s16x8*)(f2 + pA * 32 + quad * 8);
    const s16x8 a4 = *(const s16x8*)(f3 + pA * 32 + quad * 8);

    f32x4 acc[4];
#pragma unroll
    for (int nt = 0; nt < 4; ++nt) {
      f32x4 d = zf;
      d = __builtin_amdgcn_mfma_f32_16x16x32_bf16(a0, wf[0][nt], d, 0, 0, 0);
      d = __builtin_amdgcn_mfma_f32_16x16x32_bf16(a1, wf[1][nt], d, 0, 0, 0);
      d = __builtin_amdgcn_mfma_f32_16x16x32_bf16(a2, wf[2][nt], d, 0, 0, 0);
      d = __builtin_amdgcn_mfma_f32_16x16x32_bf16(a3, wf[3][nt], d, 0, 0, 0);
      d = __builtin_amdgcn_mfma_f32_16x16x32_bf16(a4, wf[4][nt], d, 0, 0, 0);
      acc[nt] = d;
    }

    // transpose through per-wave LDS: [o=64][px=16 pad 17]
#pragma unroll
    for (int nt = 0; nt < 4; ++nt)
#pragma unroll
      for (int i = 0; i < 4; ++i)
        trw[(nt * 16 + l15) * 17 + quad * 4 + i] = acc[nt][i] + bb[nt];

    const int n = p0 >> 16;
    const int pix0 = p0 & 65535;
    const float* xb = x + (size_t)n * (64 * 65536);
    float* ob = out + (size_t)n * (64 * 65536);
#pragma unroll
    for (int og = 0; og < 16; ++og) {
      const int o = og * 4 + quad;
      const float v = trw[o * 17 + l15];
      const size_t g = (size_t)o * 65536 + pix0 + l15;
      ob[g] = v + xb[g];
    }
  }
}

// ---------------------------------------------------------------------------
extern "C" void kernel_launch(void* const* d_in, const int* in_sizes, int n_in,
                              void* d_out, int out_size, void* d_ws, size_t ws_size,
                              hipStream_t stream)
{
  const float* x     = (const float*)d_in[0];
  const float* Wq    = (const float*)d_in[1];
  const float* bq    = (const float*)d_in[2];
  const float* Wk    = (const float*)d_in[3];
  const float* bk    = (const float*)d_in[4];
  const float* Wv    = (const float*)d_in[5];
  const float* bv    = (const float*)d_in[6];
  const float* Wo    = (const float*)d_in[7];
  const float* bo    = (const float*)d_in[8];
  const float* gamma = (const float*)d_in[9];
  const float* W1    = (const float*)d_in[10];
  const float* b1    = (const float*)d_in[11];
  const float* W2    = (const float*)d_in[12];
  const float* b2    = (const float*)d_in[13];
  const float* W3    = (const float*)d_in[14];
  const float* b3    = (const float*)d_in[15];
  const float* Wf    = (const float*)d_in[16];
  const float* bf    = (const float*)d_in[17];

  float* out = (float*)d_out;
  ushort_t* wsu = (ushort_t*)d_ws;

  // bf16 feature buffers, pixel-major [n][y][x][c]
  ushort_t* f0 = wsu;                       // 4*65536*64 = 16777216
  ushort_t* f1 = wsu + 16777216;            // 4*65536*32 =  8388608
  ushort_t* f2 = wsu + 25165824;
  ushort_t* f3 = wsu + 33554432;
  ushort_t* wc1 = wsu + 41943040;           // 18432
  ushort_t* wc2 = wc1 + 18432;              // 27648
  ushort_t* wc3 = wc2 + 27648;              // 36864
  ushort_t* wff = wc3 + 36864;              // 10240
  float* wkv = (float*)((char*)d_ws + 84072448);  // 4096 floats

  repack_kernel<<<144, 256, 0, stream>>>(Wk, Wv, W1, W2, W3, Wf, wkv, wc1, wc2, wc3, wff);
  attn_kernel<<<256, 256, 0, stream>>>(x, wkv, bk, bv, Wq, bq, Wo, bo, gamma, f0);
  conv3_kernel<2><<<512, 256, 0, stream>>>(f0, f1, f2, wc1, b1, f1);
  conv3_kernel<3><<<512, 256, 0, stream>>>(f0, f1, f2, wc2, b2, f2);
  conv3_kernel<4><<<512, 256, 0, stream>>>(f0, f1, f2, wc3, b3, f3);
  fuse_kernel<<<1024, 256, 0, stream>>>(f0, f1, f2, f3, x, wff, bf, out);
}